// Round 10
// baseline (261.279 us; speedup 1.0000x reference)
//
#include <hip/hip_runtime.h>
#include <hip/hip_bf16.h>
#include <stdint.h>

// MultiHeadSelfAttention, B=1, S=4096, D_MODEL=768, H=12, Dk=64, causal.
// FP32 I/O, bf16 MFMA inside. Launches:
//   0) cvt_all    fp32->bf16
//   1) gemm_nt<1> QKV -> Q,K [H][S][64], V transposed [H][64][S]
//   2) flash_part S^T flash attention; uniform work items; 16x16x16 PV;
//                 grid (NHEADS, WORK) for XCD/L2 locality; LDS-transposed
//                 coalesced epilogue stores
//   3) combine    merge <=8 chunk partials -> AO
//   4) gemm_nt<0> AO @ Wo^T -> d_out fp32
// R10: fix 9x write amplification (scalar 2B epilogue stores -> LDS transpose +
//      b128 lane-contiguous stores) and K/V L2 thrash (head-major grid: each
//      head pins to 2 XCDs since gcd(12,8)=4).

#define S_LEN  4096
#define DMODEL 768
#define NHEADS 12
#define LDSW   72          // padded LDS row stride (elems)
#define WORK   144         // work items per head

typedef __attribute__((ext_vector_type(8))) __bf16 bf16x8;
typedef __attribute__((ext_vector_type(8))) unsigned short ushortx8;
typedef __attribute__((ext_vector_type(4))) unsigned short ushortx4;
typedef __attribute__((ext_vector_type(4))) short short4v;
typedef __attribute__((ext_vector_type(2))) unsigned int uint2v;
typedef __attribute__((ext_vector_type(4))) float floatx4;

typedef __attribute__((address_space(1))) void void_g;
typedef __attribute__((address_space(3))) void void_l;

__device__ __forceinline__ unsigned short f2bf(float f) {
    unsigned int u = __float_as_uint(f);
    u += 0x7fffu + ((u >> 16) & 1u);   // RNE
    return (unsigned short)(u >> 16);
}
__device__ __forceinline__ float bf2f(unsigned short v) {
    return __uint_as_float(((unsigned int)v) << 16);
}

__device__ __forceinline__ void async_ld16(const unsigned short* g, unsigned short* l) {
    __builtin_amdgcn_global_load_lds((void_g*)g, (void_l*)l, 16, 0, 0);
}

// 16x16x16 bf16 MFMA: A-layout k=quad*4+j matches S^T C-layout rows exactly.
__device__ __forceinline__ floatx4 mfma16(short4v a, short4v b, floatx4 c) {
#if defined(__HIP_DEVICE_COMPILE__)
#if __has_builtin(__builtin_amdgcn_mfma_f32_16x16x16bf16_1k)
    return __builtin_amdgcn_mfma_f32_16x16x16bf16_1k(a, b, c, 0, 0, 0);
#else
    floatx4 d;
    asm("v_mfma_f32_16x16x16_bf16 %0, %1, %2, %3" : "=v"(d) : "v"(a), "v"(b), "v"(c));
    return d;
#endif
#else
    (void)a; (void)b;
    return c;   // host stub, never executed
#endif
}

// ---------------- fused fp32->bf16 conversion ----------------
__global__ __launch_bounds__(256) void cvt_all(
    const float* __restrict__ x,  const float* __restrict__ Wq,
    const float* __restrict__ Wk, const float* __restrict__ Wv,
    const float* __restrict__ Wo,
    unsigned short* __restrict__ xb,  unsigned short* __restrict__ Wqb,
    unsigned short* __restrict__ Wkb, unsigned short* __restrict__ Wvb,
    unsigned short* __restrict__ Wob)
{
    int b = blockIdx.x;
    const float* src; unsigned short* dst;
    if (b < 1536)      { src = x;  dst = xb;  }
    else if (b < 1824) { src = Wq; dst = Wqb; b -= 1536; }
    else if (b < 2112) { src = Wk; dst = Wkb; b -= 1824; }
    else if (b < 2400) { src = Wv; dst = Wvb; b -= 2112; }
    else               { src = Wo; dst = Wob; b -= 2400; }
    const int i = (b * 256 + threadIdx.x) * 8;
    const float4 a0 = *(const float4*)(src + i);
    const float4 a1 = *(const float4*)(src + i + 4);
    ushortx8 o;
    o[0] = f2bf(a0.x); o[1] = f2bf(a0.y); o[2] = f2bf(a0.z); o[3] = f2bf(a0.w);
    o[4] = f2bf(a1.x); o[5] = f2bf(a1.y); o[6] = f2bf(a1.z); o[7] = f2bf(a1.w);
    *(ushortx8*)(dst + i) = o;
}

// ---------------- GEMM C = A * B^T (global_load_lds staging) ----------------
template <int MODE>
__global__ __launch_bounds__(256) void gemm_nt(
    const unsigned short* __restrict__ A,
    const unsigned short* __restrict__ B0,
    const unsigned short* __restrict__ B1,
    const unsigned short* __restrict__ B2,
    unsigned short* __restrict__ C0,
    unsigned short* __restrict__ C1,
    unsigned short* __restrict__ C2,
    float* __restrict__ Cf,
    int M, int N, int K)
{
    __shared__ __align__(16) unsigned short As[128 * 32];
    __shared__ __align__(16) unsigned short Bs[128 * 32];

    const int tid  = threadIdx.x;
    const int wave = tid >> 6;
    const int lane = tid & 63;
    const int quad = lane >> 4;
    const int l16  = lane & 15;
    const int wr   = wave >> 1;
    const int wc   = wave & 1;
    const int bm   = blockIdx.y * 128;
    const int bn   = blockIdx.x * 128;

    const unsigned short* B = B0;
    unsigned short* C = C0;
    if (MODE == 1) {
        if (blockIdx.z == 1)      { B = B1; C = C1; }
        else if (blockIdx.z == 2) { B = B2; C = C2; }
    }

    floatx4 acc[4][4];
    const floatx4 zf = {0.f, 0.f, 0.f, 0.f};
#pragma unroll
    for (int i = 0; i < 4; ++i)
#pragma unroll
        for (int j = 0; j < 4; ++j) acc[i][j] = zf;

    const int srow = lane >> 2;
    const int scg  = (lane & 3) * 8;

    for (int kb = 0; kb < K; kb += 32) {
        __syncthreads();
#pragma unroll
        for (int p = 0; p < 2; ++p) {
            const int ri = p * 4 + wave;
            async_ld16(A + (size_t)(bm + ri * 16 + srow) * K + kb + scg, As + ri * 512);
            async_ld16(B + (size_t)(bn + ri * 16 + srow) * K + kb + scg, Bs + ri * 512);
        }
        __syncthreads();

        bf16x8 af[4], bfr[4];
#pragma unroll
        for (int i = 0; i < 4; ++i) {
            af[i]  = *(const bf16x8*)&As[(wr * 64 + i * 16 + l16) * 32 + quad * 8];
            bfr[i] = *(const bf16x8*)&Bs[(wc * 64 + i * 16 + l16) * 32 + quad * 8];
        }
#pragma unroll
        for (int mi = 0; mi < 4; ++mi)
#pragma unroll
            for (int ni = 0; ni < 4; ++ni)
                acc[mi][ni] = __builtin_amdgcn_mfma_f32_16x16x32_bf16(af[mi], bfr[ni], acc[mi][ni], 0, 0, 0);
    }

#pragma unroll
    for (int mi = 0; mi < 4; ++mi) {
#pragma unroll
        for (int ni = 0; ni < 4; ++ni) {
            const floatx4 v = acc[mi][ni];
            const int n = bn + wc * 64 + ni * 16 + l16;
            const int m0 = bm + wr * 64 + mi * 16 + quad * 4;
            if (MODE == 1 && blockIdx.z == 2) {
                const int hh = n >> 6, d = n & 63;
                ushortx4 pv;
#pragma unroll
                for (int r = 0; r < 4; ++r) pv[r] = f2bf(v[r]);
                *(ushortx4*)&C[(size_t)(hh * 64 + d) * M + m0] = pv;
            } else {
#pragma unroll
                for (int r = 0; r < 4; ++r) {
                    const int m = m0 + r;
                    if (MODE == 0) {
                        Cf[(size_t)m * N + n] = v[r];
                    } else {
                        const int hh = n >> 6, d = n & 63;
                        C[((size_t)hh * M + m) * 64 + d] = f2bf(v[r]);
                    }
                }
            }
        }
    }
}

// ---------------- flash attention, S^T + uniform chunks ----------------
// grid (NHEADS, WORK): linear id = h + 12*w; id mod 8 pins each head to 2 XCDs.
__global__ __launch_bounds__(256, 4) void flash_part(
    const unsigned short* __restrict__ Qh,
    const unsigned short* __restrict__ Kh,
    const unsigned short* __restrict__ VhT,   // [H][64][S]
    unsigned short* __restrict__ AO,
    unsigned short* __restrict__ Opart,
    float* __restrict__ ml)
{
    __shared__ __align__(16) unsigned short Ks[2][64 * LDSW];   // [kv][d]; reused as epilogue scratch
    __shared__ __align__(16) unsigned short Vs[2][64 * LDSW];   // [d][kv]

    const int tid  = threadIdx.x;
    const int wave = tid >> 6;
    const int lane = tid & 63;
    const int quad = lane >> 4;
    const int l16  = lane & 15;
    const int h    = blockIdx.x;
    const int w    = blockIdx.y;

    // decode work item
    int k = 0;
    while (w >= 2 * (k + 1) * (k + 2)) ++k;          // k in 0..7
    int idx = w - 2 * k * (k + 1);
    const int n = k + 1;
    int qg = 0;
    while (idx >= n) { idx -= n; ++qg; }             // qg in 0..3
    const int qb = 4 * k + qg;
    const int cc = idx;
    const int L  = 2 * qb + 2;                       // tiles for this qb
    const int tb = L / n, rem = L % n;
    const int t0 = cc * tb + (cc < rem ? cc : rem);
    const int ntiles = tb + (cc < rem ? 1 : 0);

    const int q0       = qb * 128;
    const int kv_start = t0 * 64;
    const int qbase    = q0 + wave * 32;

    const unsigned short* Qb  = Qh  + (size_t)h * S_LEN * 64;
    const unsigned short* Kb  = Kh  + (size_t)h * S_LEN * 64;
    const unsigned short* Vtb = VhT + (size_t)h * 64 * S_LEN;

    // Q B-frags (n=q=l16, k=d=quad*8+j)
    bf16x8 qf[2][2];
#pragma unroll
    for (int b = 0; b < 2; ++b)
#pragma unroll
        for (int kc = 0; kc < 2; ++kc)
            qf[b][kc] = *(const bf16x8*)&Qb[(size_t)(qbase + b * 16 + l16) * 64 + kc * 32 + quad * 8];

    float m_i[2] = {-1e30f, -1e30f}, l_i[2] = {0.f, 0.f};
    floatx4 o[2][4];
    const floatx4 zf = {0.f, 0.f, 0.f, 0.f};
#pragma unroll
    for (int b = 0; b < 2; ++b)
#pragma unroll
        for (int d = 0; d < 4; ++d) o[b][d] = zf;

    const int srow = tid >> 2;           // 0..63
    const int scol = (tid & 3) * 16;
    const int asrc = quad << 2;          // shfl src base for per-row factors

    // prologue: stage tile 0 into buf 0
    {
        const unsigned short* kp = Kb + (size_t)(kv_start + srow) * 64 + scol;
        const unsigned short* vp = Vtb + (size_t)srow * S_LEN + kv_start + scol;
        const ushortx8 k0 = *(const ushortx8*)kp;
        const ushortx8 k1 = *(const ushortx8*)(kp + 8);
        const ushortx8 v0 = *(const ushortx8*)vp;
        const ushortx8 v1 = *(const ushortx8*)(vp + 8);
        *(ushortx8*)&Ks[0][srow * LDSW + scol]     = k0;
        *(ushortx8*)&Ks[0][srow * LDSW + scol + 8] = k1;
        *(ushortx8*)&Vs[0][srow * LDSW + scol]     = v0;
        *(ushortx8*)&Vs[0][srow * LDSW + scol + 8] = v1;
    }
    __syncthreads();

    for (int t = 0; t < ntiles; ++t) {
        const int buf = t & 1;
        const int kv0 = kv_start + t * 64;
        const bool pre = (t + 1 < ntiles);

        ushortx8 kr0, kr1, vr0, vr1;
        if (pre) {
            const unsigned short* kp = Kb + (size_t)(kv0 + 64 + srow) * 64 + scol;
            const unsigned short* vp = Vtb + (size_t)srow * S_LEN + kv0 + 64 + scol;
            kr0 = *(const ushortx8*)kp;  kr1 = *(const ushortx8*)(kp + 8);
            vr0 = *(const ushortx8*)vp;  vr1 = *(const ushortx8*)(vp + 8);
        }

        if (kv0 <= qbase + 31) {   // wave has unmasked work in this tile
            // S^T = K Q^T : D[m=kv][n=q]
            floatx4 sv[2][4];
#pragma unroll
            for (int b = 0; b < 2; ++b)
#pragma unroll
                for (int ns = 0; ns < 4; ++ns) sv[b][ns] = zf;
#pragma unroll
            for (int ns = 0; ns < 4; ++ns) {
                const bf16x8 kf0 = *(const bf16x8*)&Ks[buf][(ns * 16 + l16) * LDSW + quad * 8];
                const bf16x8 kf1 = *(const bf16x8*)&Ks[buf][(ns * 16 + l16) * LDSW + 32 + quad * 8];
                sv[0][ns] = __builtin_amdgcn_mfma_f32_16x16x32_bf16(kf0, qf[0][0], sv[0][ns], 0, 0, 0);
                sv[0][ns] = __builtin_amdgcn_mfma_f32_16x16x32_bf16(kf1, qf[0][1], sv[0][ns], 0, 0, 0);
                sv[1][ns] = __builtin_amdgcn_mfma_f32_16x16x32_bf16(kf0, qf[1][0], sv[1][ns], 0, 0, 0);
                sv[1][ns] = __builtin_amdgcn_mfma_f32_16x16x32_bf16(kf1, qf[1][1], sv[1][ns], 0, 0, 0);
            }

            const bool domask = (kv0 + 63 > qbase);
            unsigned int pk[2][4][2];
            float al[2];
#pragma unroll
            for (int b = 0; b < 2; ++b) {
                const int qcol = qbase + b * 16 + l16;
                if (domask) {
#pragma unroll
                    for (int ns = 0; ns < 4; ++ns)
#pragma unroll
                        for (int r = 0; r < 4; ++r) {
                            float v = sv[b][ns][r] * 0.125f;
                            if (kv0 + ns * 16 + quad * 4 + r > qcol) v = -1e9f;
                            sv[b][ns][r] = v;
                        }
                } else {
#pragma unroll
                    for (int ns = 0; ns < 4; ++ns)
#pragma unroll
                        for (int r = 0; r < 4; ++r)
                            sv[b][ns][r] = sv[b][ns][r] * 0.125f;
                }
                float mx = sv[b][0][0];
#pragma unroll
                for (int ns = 0; ns < 4; ++ns)
#pragma unroll
                    for (int r = 0; r < 4; ++r) mx = fmaxf(mx, sv[b][ns][r]);
                mx = fmaxf(mx, __shfl_xor(mx, 16, 64));
                mx = fmaxf(mx, __shfl_xor(mx, 32, 64));
                const float mn = fmaxf(m_i[b], mx);
                al[b] = __expf(m_i[b] - mn);
                m_i[b] = mn;
                float rs = 0.f;
#pragma unroll
                for (int ns = 0; ns < 4; ++ns)
#pragma unroll
                    for (int r = 0; r < 4; ++r) {
                        const float p = __expf(sv[b][ns][r] - mn);
                        sv[b][ns][r] = p;
                        rs += p;
                    }
                rs += __shfl_xor(rs, 16, 64);
                rs += __shfl_xor(rs, 32, 64);
                l_i[b] = l_i[b] * al[b] + rs;
                // pack P pairs (trunc) -> A-frags for 16x16x16 (k = quad*4+j)
#pragma unroll
                for (int ns = 0; ns < 4; ++ns)
#pragma unroll
                    for (int rr = 0; rr < 2; ++rr)
                        pk[b][ns][rr] = (__float_as_uint(sv[b][ns][2 * rr + 1]) & 0xffff0000u)
                                      | (__float_as_uint(sv[b][ns][2 * rr]) >> 16);
                // rescale O rows (row q = quad*4+r; factor from lane quad*4+r)
#pragma unroll
                for (int r = 0; r < 4; ++r) {
                    const float a = __shfl(al[b], asrc + r, 64);
#pragma unroll
                    for (int d = 0; d < 4; ++d) o[b][d][r] *= a;
                }
            }

            // O += P V via 16x16x16: A = P (no cross-lane!), B = V^T b64 from LDS
#pragma unroll
            for (int ns = 0; ns < 4; ++ns) {
                if (kv0 + ns * 16 <= qbase + 31) {   // skip fully-masked 16-kv subtile
                    const uint2v u0 = {pk[0][ns][0], pk[0][ns][1]};
                    const uint2v u1 = {pk[1][ns][0], pk[1][ns][1]};
                    const short4v pa0 = __builtin_bit_cast(short4v, u0);
                    const short4v pa1 = __builtin_bit_cast(short4v, u1);
#pragma unroll
                    for (int db = 0; db < 4; ++db) {
                        const short4v vb = *(const short4v*)&Vs[buf][(db * 16 + l16) * LDSW + ns * 16 + quad * 4];
                        o[0][db] = mfma16(pa0, vb, o[0][db]);
                        o[1][db] = mfma16(pa1, vb, o[1][db]);
                    }
                }
            }
        }

        if (pre) {
            *(ushortx8*)&Ks[buf ^ 1][srow * LDSW + scol]     = kr0;
            *(ushortx8*)&Ks[buf ^ 1][srow * LDSW + scol + 8] = kr1;
            *(ushortx8*)&Vs[buf ^ 1][srow * LDSW + scol]     = vr0;
            *(ushortx8*)&Vs[buf ^ 1][srow * LDSW + scol + 8] = vr1;
        }
        __syncthreads();
    }

    // ---- epilogue: stage O in LDS [128][64], then coalesced global stores ----
    unsigned short* T = &Ks[0][0];   // 16 KB scratch (safe: last barrier passed)
    {
        float scl[2];
        scl[0] = (k == 0) ? (1.0f / l_i[0]) : 1.0f;
        scl[1] = (k == 0) ? (1.0f / l_i[1]) : 1.0f;
#pragma unroll
        for (int b = 0; b < 2; ++b)
#pragma unroll
            for (int r = 0; r < 4; ++r) {
                const float a = __shfl(scl[b], asrc + r, 64);
                const int row = wave * 32 + b * 16 + quad * 4 + r;
#pragma unroll
                for (int d = 0; d < 4; ++d)
                    T[row * 64 + d * 16 + l16] = f2bf(o[b][d][r] * a);
            }
    }
    __syncthreads();

    if (k == 0) {
        // direct normalized write to AO
#pragma unroll
        for (int g = 0; g < 4; ++g) {
            const int row = g * 32 + (tid >> 3);
            const int col = (tid & 7) * 8;
            const ushortx8 v = *(const ushortx8*)&T[row * 64 + col];
            *(ushortx8*)&AO[(size_t)(q0 + row) * DMODEL + h * 64 + col] = v;
        }
    } else {
        const int slot = h * WORK + w;
        unsigned short* op = Opart + (size_t)slot * (128 * 64);
#pragma unroll
        for (int g = 0; g < 4; ++g) {
            const int c = g * 256 + tid;             // 16B chunk index
            const ushortx8 v = *(const ushortx8*)&T[c * 8];
            *(ushortx8*)&op[c * 8] = v;              // lane-contiguous 16B stores
        }
        if (quad == 0) {
            float* mlp = ml + (size_t)slot * 256;
#pragma unroll
            for (int b = 0; b < 2; ++b) {
                const int lr = wave * 32 + b * 16 + l16;
                mlp[lr * 2]     = m_i[b];
                mlp[lr * 2 + 1] = l_i[b];
            }
        }
    }
}

// ---------------- combine chunk partials ----------------
// grid (28, 12): qb = 4 + bx. n = (qb>>2)+1 chunks, slots w0..w0+n-1.
__global__ __launch_bounds__(256) void combine(
    const unsigned short* __restrict__ Opart,
    const float* __restrict__ ml,
    unsigned short* __restrict__ AO)
{
    const int qb  = 4 + blockIdx.x;
    const int h   = blockIdx.y;
    const int row = threadIdx.x >> 1;
    const int ds  = (threadIdx.x & 1) * 32;
    const int k   = qb >> 2;
    const int n   = k + 1;
    const int w0  = 2 * k * (k + 1) + (qb & 3) * n;

    float mc[8], lc[8];
    float M = -3e38f;
    for (int cI = 0; cI < n; ++cI) {
        const size_t slot = (size_t)h * WORK + w0 + cI;
        mc[cI] = ml[slot * 256 + row * 2];
        lc[cI] = ml[slot * 256 + row * 2 + 1];
        M = fmaxf(M, mc[cI]);
    }
    float L = 0.f;
    float acc[32];
#pragma unroll
    for (int i = 0; i < 32; ++i) acc[i] = 0.f;

    for (int cI = 0; cI < n; ++cI) {
        const float sc = __expf(mc[cI] - M);
        L += sc * lc[cI];
        const unsigned short* op = Opart + ((size_t)h * WORK + w0 + cI) * (128 * 64) + row * 64 + ds;
#pragma unroll
        for (int g = 0; g < 4; ++g) {
            const ushortx8 a = *(const ushortx8*)(op + g * 8);
#pragma unroll
            for (int i = 0; i < 8; ++i) acc[g * 8 + i] += sc * bf2f(a[i]);
        }
    }
    const float inv = 1.0f / L;
    unsigned short* dst = AO + (size_t)(qb * 128 + row) * DMODEL + h * 64 + ds;
#pragma unroll
    for (int g = 0; g < 4; ++g) {
        ushortx8 ov;
#pragma unroll
        for (int i = 0; i < 8; ++i) ov[i] = f2bf(acc[g * 8 + i] * inv);
        *(ushortx8*)(dst + g * 8) = ov;
    }
}

extern "C" void kernel_launch(void* const* d_in, const int* in_sizes, int n_in,
                              void* d_out, int out_size, void* d_ws, size_t ws_size,
                              hipStream_t stream) {
    const float* x  = (const float*)d_in[0];
    const float* Wq = (const float*)d_in[1];
    const float* Wk = (const float*)d_in[2];
    const float* Wv = (const float*)d_in[3];
    const float* Wo = (const float*)d_in[4];

    const int xElems = S_LEN * DMODEL;
    const int wElems = DMODEL * DMODEL;
    const size_t headElems = (size_t)NHEADS * S_LEN * 64;
    const int nslots = NHEADS * WORK;   // 1728

    unsigned short* xb  = (unsigned short*)d_ws;
    unsigned short* Wqb = xb  + xElems;
    unsigned short* Wkb = Wqb + wElems;
    unsigned short* Wvb = Wkb + wElems;
    unsigned short* Wob = Wvb + wElems;
    unsigned short* Qh  = Wob + wElems;
    unsigned short* Kh  = Qh + headElems;
    unsigned short* Vt  = Kh + headElems;                    // [H][64][S]
    unsigned short* AO  = Vt + headElems;
    unsigned short* Opart = AO + xElems;                     // [1728][128*64]
    float* ml = (float*)(Opart + (size_t)nslots * 128 * 64); // [1728][256]

    cvt_all<<<dim3(2688), dim3(256), 0, stream>>>(x, Wq, Wk, Wv, Wo,
                                                  xb, Wqb, Wkb, Wvb, Wob);

    gemm_nt<1><<<dim3(DMODEL / 128, S_LEN / 128, 3), dim3(256), 0, stream>>>(
        xb, Wqb, Wkb, Wvb, Qh, Kh, Vt, nullptr, S_LEN, DMODEL, DMODEL);

    flash_part<<<dim3(NHEADS, WORK), dim3(256), 0, stream>>>(Qh, Kh, Vt, AO, Opart, ml);

    combine<<<dim3(28, NHEADS), dim3(256), 0, stream>>>(Opart, ml, AO);

    gemm_nt<0><<<dim3(DMODEL / 128, S_LEN / 128, 1), dim3(256), 0, stream>>>(
        AO, Wob, nullptr, nullptr, nullptr, nullptr, nullptr,
        (float*)d_out, S_LEN, DMODEL, DMODEL);
}

// Round 11
// 225.140 us; speedup vs baseline: 1.1605x; 1.1605x over previous
//
#include <hip/hip_runtime.h>
#include <hip/hip_bf16.h>
#include <stdint.h>

// MultiHeadSelfAttention, B=1, S=4096, D_MODEL=768, H=12, Dk=64, causal.
// FP32 I/O, bf16 MFMA inside. Launches:
//   0) cvt_all    fp32->bf16
//   1) gemm_nt<1> QKV -> Q,K [H][S][64], V transposed [H][64][S]
//   2) flash_part S^T flash attention; Q-tile 256 (512 thr, 8 waves x 32 q);
//                 uniform KV chunks of 4-8 tiles; 16x16x16 PV; LDS epilogue
//   3) combine    merge 2..8 chunk partials -> AO
//   4) gemm_nt<0> AO @ Wo^T -> d_out fp32
// R11: Q-tile 128->256 halves raw staged KV (198->102 MB) — R9/R10 regression
//      traced to L2 thrash (WRITE_SIZE tracks L2 victims, not stores); removed
//      launch_bounds(,4) (fewer concurrent KV windows), same-head dispatch order.

#define S_LEN  4096
#define DMODEL 768
#define NHEADS 12
#define LDSW   72          // padded LDS row stride (elems)
#define WORK   72          // work items per head (Q-tile 256)
#define TILEQ  256

typedef __attribute__((ext_vector_type(8))) __bf16 bf16x8;
typedef __attribute__((ext_vector_type(8))) unsigned short ushortx8;
typedef __attribute__((ext_vector_type(4))) unsigned short ushortx4;
typedef __attribute__((ext_vector_type(4))) short short4v;
typedef __attribute__((ext_vector_type(2))) unsigned int uint2v;
typedef __attribute__((ext_vector_type(4))) float floatx4;

typedef __attribute__((address_space(1))) void void_g;
typedef __attribute__((address_space(3))) void void_l;

__device__ __forceinline__ unsigned short f2bf(float f) {
    unsigned int u = __float_as_uint(f);
    u += 0x7fffu + ((u >> 16) & 1u);   // RNE
    return (unsigned short)(u >> 16);
}
__device__ __forceinline__ float bf2f(unsigned short v) {
    return __uint_as_float(((unsigned int)v) << 16);
}

__device__ __forceinline__ void async_ld16(const unsigned short* g, unsigned short* l) {
    __builtin_amdgcn_global_load_lds((void_g*)g, (void_l*)l, 16, 0, 0);
}

// 16x16x16 bf16 MFMA: A-layout k=quad*4+j matches S^T C-layout rows exactly.
__device__ __forceinline__ floatx4 mfma16(short4v a, short4v b, floatx4 c) {
#if defined(__HIP_DEVICE_COMPILE__)
#if __has_builtin(__builtin_amdgcn_mfma_f32_16x16x16bf16_1k)
    return __builtin_amdgcn_mfma_f32_16x16x16bf16_1k(a, b, c, 0, 0, 0);
#else
    floatx4 d;
    asm("v_mfma_f32_16x16x16_bf16 %0, %1, %2, %3" : "=v"(d) : "v"(a), "v"(b), "v"(c));
    return d;
#endif
#else
    (void)a; (void)b;
    return c;   // host stub, never executed
#endif
}

// ---------------- fused fp32->bf16 conversion ----------------
__global__ __launch_bounds__(256) void cvt_all(
    const float* __restrict__ x,  const float* __restrict__ Wq,
    const float* __restrict__ Wk, const float* __restrict__ Wv,
    const float* __restrict__ Wo,
    unsigned short* __restrict__ xb,  unsigned short* __restrict__ Wqb,
    unsigned short* __restrict__ Wkb, unsigned short* __restrict__ Wvb,
    unsigned short* __restrict__ Wob)
{
    int b = blockIdx.x;
    const float* src; unsigned short* dst;
    if (b < 1536)      { src = x;  dst = xb;  }
    else if (b < 1824) { src = Wq; dst = Wqb; b -= 1536; }
    else if (b < 2112) { src = Wk; dst = Wkb; b -= 1824; }
    else if (b < 2400) { src = Wv; dst = Wvb; b -= 2112; }
    else               { src = Wo; dst = Wob; b -= 2400; }
    const int i = (b * 256 + threadIdx.x) * 8;
    const float4 a0 = *(const float4*)(src + i);
    const float4 a1 = *(const float4*)(src + i + 4);
    ushortx8 o;
    o[0] = f2bf(a0.x); o[1] = f2bf(a0.y); o[2] = f2bf(a0.z); o[3] = f2bf(a0.w);
    o[4] = f2bf(a1.x); o[5] = f2bf(a1.y); o[6] = f2bf(a1.z); o[7] = f2bf(a1.w);
    *(ushortx8*)(dst + i) = o;
}

// ---------------- GEMM C = A * B^T (global_load_lds staging) ----------------
template <int MODE>
__global__ __launch_bounds__(256) void gemm_nt(
    const unsigned short* __restrict__ A,
    const unsigned short* __restrict__ B0,
    const unsigned short* __restrict__ B1,
    const unsigned short* __restrict__ B2,
    unsigned short* __restrict__ C0,
    unsigned short* __restrict__ C1,
    unsigned short* __restrict__ C2,
    float* __restrict__ Cf,
    int M, int N, int K)
{
    __shared__ __align__(16) unsigned short As[128 * 32];
    __shared__ __align__(16) unsigned short Bs[128 * 32];

    const int tid  = threadIdx.x;
    const int wave = tid >> 6;
    const int lane = tid & 63;
    const int quad = lane >> 4;
    const int l16  = lane & 15;
    const int wr   = wave >> 1;
    const int wc   = wave & 1;
    const int bm   = blockIdx.y * 128;
    const int bn   = blockIdx.x * 128;

    const unsigned short* B = B0;
    unsigned short* C = C0;
    if (MODE == 1) {
        if (blockIdx.z == 1)      { B = B1; C = C1; }
        else if (blockIdx.z == 2) { B = B2; C = C2; }
    }

    floatx4 acc[4][4];
    const floatx4 zf = {0.f, 0.f, 0.f, 0.f};
#pragma unroll
    for (int i = 0; i < 4; ++i)
#pragma unroll
        for (int j = 0; j < 4; ++j) acc[i][j] = zf;

    const int srow = lane >> 2;
    const int scg  = (lane & 3) * 8;

    for (int kb = 0; kb < K; kb += 32) {
        __syncthreads();
#pragma unroll
        for (int p = 0; p < 2; ++p) {
            const int ri = p * 4 + wave;
            async_ld16(A + (size_t)(bm + ri * 16 + srow) * K + kb + scg, As + ri * 512);
            async_ld16(B + (size_t)(bn + ri * 16 + srow) * K + kb + scg, Bs + ri * 512);
        }
        __syncthreads();

        bf16x8 af[4], bfr[4];
#pragma unroll
        for (int i = 0; i < 4; ++i) {
            af[i]  = *(const bf16x8*)&As[(wr * 64 + i * 16 + l16) * 32 + quad * 8];
            bfr[i] = *(const bf16x8*)&Bs[(wc * 64 + i * 16 + l16) * 32 + quad * 8];
        }
#pragma unroll
        for (int mi = 0; mi < 4; ++mi)
#pragma unroll
            for (int ni = 0; ni < 4; ++ni)
                acc[mi][ni] = __builtin_amdgcn_mfma_f32_16x16x32_bf16(af[mi], bfr[ni], acc[mi][ni], 0, 0, 0);
    }

#pragma unroll
    for (int mi = 0; mi < 4; ++mi) {
#pragma unroll
        for (int ni = 0; ni < 4; ++ni) {
            const floatx4 v = acc[mi][ni];
            const int n = bn + wc * 64 + ni * 16 + l16;
            const int m0 = bm + wr * 64 + mi * 16 + quad * 4;
            if (MODE == 1 && blockIdx.z == 2) {
                const int hh = n >> 6, d = n & 63;
                ushortx4 pv;
#pragma unroll
                for (int r = 0; r < 4; ++r) pv[r] = f2bf(v[r]);
                *(ushortx4*)&C[(size_t)(hh * 64 + d) * M + m0] = pv;
            } else {
#pragma unroll
                for (int r = 0; r < 4; ++r) {
                    const int m = m0 + r;
                    if (MODE == 0) {
                        Cf[(size_t)m * N + n] = v[r];
                    } else {
                        const int hh = n >> 6, d = n & 63;
                        C[((size_t)hh * M + m) * 64 + d] = f2bf(v[r]);
                    }
                }
            }
        }
    }
}

// ---------------- flash attention: Q-tile 256, S^T, uniform chunks ----------------
// grid (WORK, NHEADS), 512 thr = 8 waves x 32 q. Item w -> (qb, chunk cc):
// chunks per qb n = (qb+2)>>1; tiles L = 4(qb+1) split evenly (4..8 per item).
__global__ __launch_bounds__(512) void flash_part(
    const unsigned short* __restrict__ Qh,
    const unsigned short* __restrict__ Kh,
    const unsigned short* __restrict__ VhT,   // [H][64][S]
    unsigned short* __restrict__ AO,
    unsigned short* __restrict__ Opart,       // [H*WORK][256*64]
    float* __restrict__ ml)                   // [H*WORK][512]
{
    __shared__ __align__(16) unsigned short SM[4 * 64 * LDSW];   // 36 KB arena
    // Ks[buf] = SM + buf*4608, Vs[buf] = SM + (2+buf)*4608; epilogue T = SM (32 KB)

    const int tid  = threadIdx.x;
    const int wave = tid >> 6;
    const int lane = tid & 63;
    const int quad = lane >> 4;
    const int l16  = lane & 15;
    const int h    = blockIdx.y;
    const int w    = blockIdx.x;

    // decode work item
    int qb = 0, rw = w;
    while (rw >= ((qb + 2) >> 1)) { rw -= (qb + 2) >> 1; ++qb; }   // qb 0..15
    const int cc = rw;
    const int n  = (qb + 2) >> 1;
    const int L  = 4 * (qb + 1);
    const int tb = L / n, rem = L % n;
    const int t0 = cc * tb + (cc < rem ? cc : rem);
    const int ntiles = tb + (cc < rem ? 1 : 0);

    const int q0       = qb * TILEQ;
    const int kv_start = t0 * 64;
    const int qbase    = q0 + wave * 32;

    const unsigned short* Qb  = Qh  + (size_t)h * S_LEN * 64;
    const unsigned short* Kb  = Kh  + (size_t)h * S_LEN * 64;
    const unsigned short* Vtb = VhT + (size_t)h * 64 * S_LEN;

    // Q B-frags (n=q=l16, k=d=quad*8+j)
    bf16x8 qf[2][2];
#pragma unroll
    for (int b = 0; b < 2; ++b)
#pragma unroll
        for (int kc = 0; kc < 2; ++kc)
            qf[b][kc] = *(const bf16x8*)&Qb[(size_t)(qbase + b * 16 + l16) * 64 + kc * 32 + quad * 8];

    float m_i[2] = {-1e30f, -1e30f}, l_i[2] = {0.f, 0.f};
    floatx4 o[2][4];
    const floatx4 zf = {0.f, 0.f, 0.f, 0.f};
#pragma unroll
    for (int b = 0; b < 2; ++b)
#pragma unroll
        for (int d = 0; d < 4; ++d) o[b][d] = zf;

    const int srow = tid >> 3;           // 0..63
    const int scol = (tid & 7) * 8;      // 8-elem chunk
    const int asrc = quad << 2;          // shfl src base for per-row factors

    // prologue: stage tile 0 into buf 0 (one 16B load per thread per array)
    {
        const ushortx8 k0 = *(const ushortx8*)(Kb + (size_t)(kv_start + srow) * 64 + scol);
        const ushortx8 v0 = *(const ushortx8*)(Vtb + (size_t)srow * S_LEN + kv_start + scol);
        *(ushortx8*)&SM[0 * 4608 + srow * LDSW + scol] = k0;
        *(ushortx8*)&SM[2 * 4608 + srow * LDSW + scol] = v0;
    }
    __syncthreads();

    for (int t = 0; t < ntiles; ++t) {
        const int buf = t & 1;
        const int kv0 = kv_start + t * 64;
        const bool pre = (t + 1 < ntiles);
        const unsigned short* Ksb = SM + buf * 4608;
        const unsigned short* Vsb = SM + (2 + buf) * 4608;

        ushortx8 kr, vr;
        if (pre) {
            kr = *(const ushortx8*)(Kb + (size_t)(kv0 + 64 + srow) * 64 + scol);
            vr = *(const ushortx8*)(Vtb + (size_t)srow * S_LEN + kv0 + 64 + scol);
        }

        if (kv0 <= qbase + 31) {   // wave has unmasked work in this tile
            // S^T = K Q^T : D[m=kv][n=q]
            floatx4 sv[2][4];
#pragma unroll
            for (int b = 0; b < 2; ++b)
#pragma unroll
                for (int ns = 0; ns < 4; ++ns) sv[b][ns] = zf;
#pragma unroll
            for (int ns = 0; ns < 4; ++ns) {
                const bf16x8 kf0 = *(const bf16x8*)&Ksb[(ns * 16 + l16) * LDSW + quad * 8];
                const bf16x8 kf1 = *(const bf16x8*)&Ksb[(ns * 16 + l16) * LDSW + 32 + quad * 8];
                sv[0][ns] = __builtin_amdgcn_mfma_f32_16x16x32_bf16(kf0, qf[0][0], sv[0][ns], 0, 0, 0);
                sv[0][ns] = __builtin_amdgcn_mfma_f32_16x16x32_bf16(kf1, qf[0][1], sv[0][ns], 0, 0, 0);
                sv[1][ns] = __builtin_amdgcn_mfma_f32_16x16x32_bf16(kf0, qf[1][0], sv[1][ns], 0, 0, 0);
                sv[1][ns] = __builtin_amdgcn_mfma_f32_16x16x32_bf16(kf1, qf[1][1], sv[1][ns], 0, 0, 0);
            }

            const bool domask = (kv0 + 63 > qbase);
            unsigned int pk[2][4][2];
            float al[2];
#pragma unroll
            for (int b = 0; b < 2; ++b) {
                const int qcol = qbase + b * 16 + l16;
                if (domask) {
#pragma unroll
                    for (int ns = 0; ns < 4; ++ns)
#pragma unroll
                        for (int r = 0; r < 4; ++r) {
                            float v = sv[b][ns][r] * 0.125f;
                            if (kv0 + ns * 16 + quad * 4 + r > qcol) v = -1e9f;
                            sv[b][ns][r] = v;
                        }
                } else {
#pragma unroll
                    for (int ns = 0; ns < 4; ++ns)
#pragma unroll
                        for (int r = 0; r < 4; ++r)
                            sv[b][ns][r] = sv[b][ns][r] * 0.125f;
                }
                float mx = sv[b][0][0];
#pragma unroll
                for (int ns = 0; ns < 4; ++ns)
#pragma unroll
                    for (int r = 0; r < 4; ++r) mx = fmaxf(mx, sv[b][ns][r]);
                mx = fmaxf(mx, __shfl_xor(mx, 16, 64));
                mx = fmaxf(mx, __shfl_xor(mx, 32, 64));
                const float mn = fmaxf(m_i[b], mx);
                al[b] = __expf(m_i[b] - mn);
                m_i[b] = mn;
                float rs = 0.f;
#pragma unroll
                for (int ns = 0; ns < 4; ++ns)
#pragma unroll
                    for (int r = 0; r < 4; ++r) {
                        const float p = __expf(sv[b][ns][r] - mn);
                        sv[b][ns][r] = p;
                        rs += p;
                    }
                rs += __shfl_xor(rs, 16, 64);
                rs += __shfl_xor(rs, 32, 64);
                l_i[b] = l_i[b] * al[b] + rs;
#pragma unroll
                for (int ns = 0; ns < 4; ++ns)
#pragma unroll
                    for (int rr = 0; rr < 2; ++rr)
                        pk[b][ns][rr] = (__float_as_uint(sv[b][ns][2 * rr + 1]) & 0xffff0000u)
                                      | (__float_as_uint(sv[b][ns][2 * rr]) >> 16);
#pragma unroll
                for (int r = 0; r < 4; ++r) {
                    const float a = __shfl(al[b], asrc + r, 64);
#pragma unroll
                    for (int d = 0; d < 4; ++d) o[b][d][r] *= a;
                }
            }

            // O += P V via 16x16x16: A = P in-reg, B = V^T b64 from LDS
#pragma unroll
            for (int ns = 0; ns < 4; ++ns) {
                if (kv0 + ns * 16 <= qbase + 31) {
                    const uint2v u0 = {pk[0][ns][0], pk[0][ns][1]};
                    const uint2v u1 = {pk[1][ns][0], pk[1][ns][1]};
                    const short4v pa0 = __builtin_bit_cast(short4v, u0);
                    const short4v pa1 = __builtin_bit_cast(short4v, u1);
#pragma unroll
                    for (int db = 0; db < 4; ++db) {
                        const short4v vb = *(const short4v*)&Vsb[(db * 16 + l16) * LDSW + ns * 16 + quad * 4];
                        o[0][db] = mfma16(pa0, vb, o[0][db]);
                        o[1][db] = mfma16(pa1, vb, o[1][db]);
                    }
                }
            }
        }

        if (pre) {
            *(ushortx8*)&SM[(buf ^ 1) * 4608 + srow * LDSW + scol]       = kr;
            *(ushortx8*)&SM[(2 + (buf ^ 1)) * 4608 + srow * LDSW + scol] = vr;
        }
        __syncthreads();
    }

    // ---- epilogue: O -> LDS [256][64] -> coalesced global stores ----
    unsigned short* T = SM;   // 32 KB scratch
    {
        float scl[2];
        scl[0] = (n == 1) ? (1.0f / l_i[0]) : 1.0f;
        scl[1] = (n == 1) ? (1.0f / l_i[1]) : 1.0f;
#pragma unroll
        for (int b = 0; b < 2; ++b)
#pragma unroll
            for (int r = 0; r < 4; ++r) {
                const float a = __shfl(scl[b], asrc + r, 64);
                const int row = wave * 32 + b * 16 + quad * 4 + r;
#pragma unroll
                for (int d = 0; d < 4; ++d)
                    T[row * 64 + d * 16 + l16] = f2bf(o[b][d][r] * a);
            }
    }
    __syncthreads();

    if (n == 1) {
        // single chunk (qb 0,1): direct normalized write to AO
#pragma unroll
        for (int g = 0; g < 4; ++g) {
            const int row = g * 64 + (tid >> 3);
            const int col = (tid & 7) * 8;
            const ushortx8 v = *(const ushortx8*)&T[row * 64 + col];
            *(ushortx8*)&AO[(size_t)(q0 + row) * DMODEL + h * 64 + col] = v;
        }
    } else {
        const int slot = h * WORK + w;
        unsigned short* op = Opart + (size_t)slot * (TILEQ * 64);
#pragma unroll
        for (int g = 0; g < 4; ++g) {
            const int c = g * 512 + tid;
            const ushortx8 v = *(const ushortx8*)&T[c * 8];
            *(ushortx8*)&op[c * 8] = v;
        }
        if (quad == 0) {
            float* mlp = ml + (size_t)slot * 512;
#pragma unroll
            for (int b = 0; b < 2; ++b) {
                const int lr = wave * 32 + b * 16 + l16;
                mlp[lr * 2]     = m_i[b];
                mlp[lr * 2 + 1] = l_i[b];
            }
        }
    }
}

// ---------------- combine chunk partials ----------------
// grid (14, 12): qb = 2 + bx (2..15), n = (qb+2)>>1 chunks.
__global__ __launch_bounds__(256) void combine(
    const unsigned short* __restrict__ Opart,
    const float* __restrict__ ml,
    unsigned short* __restrict__ AO)
{
    const int qb = 2 + blockIdx.x;
    const int h  = blockIdx.y;
    const int n  = (qb + 2) >> 1;
    int w0 = 0;
    for (int j = 0; j < qb; ++j) w0 += (j + 2) >> 1;

    const int ds = (threadIdx.x & 1) * 32;

    for (int g = 0; g < 2; ++g) {
        const int row = g * 128 + (threadIdx.x >> 1);
        float mc[8], lc[8];
        float M = -3e38f;
        for (int cI = 0; cI < n; ++cI) {
            const size_t slot = (size_t)h * WORK + w0 + cI;
            mc[cI] = ml[slot * 512 + row * 2];
            lc[cI] = ml[slot * 512 + row * 2 + 1];
            M = fmaxf(M, mc[cI]);
        }
        float L = 0.f;
        float acc[32];
#pragma unroll
        for (int i = 0; i < 32; ++i) acc[i] = 0.f;

        for (int cI = 0; cI < n; ++cI) {
            const float sc = __expf(mc[cI] - M);
            L += sc * lc[cI];
            const unsigned short* op = Opart + ((size_t)h * WORK + w0 + cI) * (TILEQ * 64)
                                     + row * 64 + ds;
#pragma unroll
            for (int gg = 0; gg < 4; ++gg) {
                const ushortx8 a = *(const ushortx8*)(op + gg * 8);
#pragma unroll
                for (int i = 0; i < 8; ++i) acc[gg * 8 + i] += sc * bf2f(a[i]);
            }
        }
        const float inv = 1.0f / L;
        unsigned short* dst = AO + (size_t)(qb * TILEQ + row) * DMODEL + h * 64 + ds;
#pragma unroll
        for (int gg = 0; gg < 4; ++gg) {
            ushortx8 ov;
#pragma unroll
            for (int i = 0; i < 8; ++i) ov[i] = f2bf(acc[gg * 8 + i] * inv);
            *(ushortx8*)(dst + gg * 8) = ov;
        }
    }
}

extern "C" void kernel_launch(void* const* d_in, const int* in_sizes, int n_in,
                              void* d_out, int out_size, void* d_ws, size_t ws_size,
                              hipStream_t stream) {
    const float* x  = (const float*)d_in[0];
    const float* Wq = (const float*)d_in[1];
    const float* Wk = (const float*)d_in[2];
    const float* Wv = (const float*)d_in[3];
    const float* Wo = (const float*)d_in[4];

    const int xElems = S_LEN * DMODEL;
    const int wElems = DMODEL * DMODEL;
    const size_t headElems = (size_t)NHEADS * S_LEN * 64;
    const int nslots = NHEADS * WORK;   // 864

    unsigned short* xb  = (unsigned short*)d_ws;
    unsigned short* Wqb = xb  + xElems;
    unsigned short* Wkb = Wqb + wElems;
    unsigned short* Wvb = Wkb + wElems;
    unsigned short* Wob = Wvb + wElems;
    unsigned short* Qh  = Wob + wElems;
    unsigned short* Kh  = Qh + headElems;
    unsigned short* Vt  = Kh + headElems;                        // [H][64][S]
    unsigned short* AO  = Vt + headElems;
    unsigned short* Opart = AO + xElems;                         // [864][256*64]
    float* ml = (float*)(Opart + (size_t)nslots * TILEQ * 64);   // [864][512]

    cvt_all<<<dim3(2688), dim3(256), 0, stream>>>(x, Wq, Wk, Wv, Wo,
                                                  xb, Wqb, Wkb, Wvb, Wob);

    gemm_nt<1><<<dim3(DMODEL / 128, S_LEN / 128, 3), dim3(256), 0, stream>>>(
        xb, Wqb, Wkb, Wvb, Qh, Kh, Vt, nullptr, S_LEN, DMODEL, DMODEL);

    flash_part<<<dim3(WORK, NHEADS), dim3(512), 0, stream>>>(Qh, Kh, Vt, AO, Opart, ml);

    combine<<<dim3(14, NHEADS), dim3(256), 0, stream>>>(Opart, ml, AO);

    gemm_nt<0><<<dim3(DMODEL / 128, S_LEN / 128, 1), dim3(256), 0, stream>>>(
        AO, Wob, nullptr, nullptr, nullptr, nullptr, nullptr,
        (float*)d_out, S_LEN, DMODEL, DMODEL);
}